// Round 5
// baseline (278.804 us; speedup 1.0000x reference)
//
#include <hip/hip_runtime.h>
#include <math.h>

#define BB 2
#define LL 2048
#define DD 1024
#define HH 16
#define DHD 64
#define NT (BB*LL)
#define D3 (3*DD)
#define D2 (2*DD)
#define NSPLIT 4
#define KVCH (LL/NSPLIT)     // 512 kv rows per split

typedef __bf16 bf16x8 __attribute__((ext_vector_type(8)));
typedef float  f32x4  __attribute__((ext_vector_type(4)));

__device__ __forceinline__ f32x4 mfma16(bf16x8 a, bf16x8 b, f32x4 c) {
    return __builtin_amdgcn_mfma_f32_16x16x32_bf16(a, b, c, 0, 0, 0);
}

__device__ __forceinline__ unsigned short f2bf(float f) {
    unsigned int u = __float_as_uint(f);
    u = (u + 0x7FFFu + ((u >> 16) & 1u)) >> 16;
    return (unsigned short)u;
}
__device__ __forceinline__ float bf2f(unsigned short s) {
    return __uint_as_float(((unsigned int)s) << 16);
}

__device__ __forceinline__ void gload16(const void* g, void* l) {
    __builtin_amdgcn_global_load_lds(
        (const __attribute__((address_space(1))) void*)g,
        (__attribute__((address_space(3))) void*)l, 16, 0, 0);
}

__device__ __forceinline__ float wred(float v) {
#pragma unroll
    for (int off = 32; off > 0; off >>= 1) v += __shfl_down(v, off, 64);
    return v;
}

// pack two positive fp32 -> bf16 pair (round-half-up) in 3 VALU ops
__device__ __forceinline__ unsigned int pack_bf2(float p0, float p1) {
    const unsigned int u0 = __float_as_uint(p0) + 0x8000u;
    const unsigned int u1 = __float_as_uint(p1) + 0x8000u;
    return __builtin_amdgcn_perm(u1, u0, 0x07060302u);  // [u1.hi16 : u0.hi16]
}

// -------------------- fused LayerNorm (blocks 0..NT-1) + weight cvt ----------
__global__ __launch_bounds__(256) void ln_cvt_kernel(
        const float* __restrict__ x, const float* __restrict__ w,
        const float* __restrict__ b, unsigned short* __restrict__ h,
        const float* __restrict__ wq, unsigned short* __restrict__ wqb,
        const float* __restrict__ wo, unsigned short* __restrict__ wob) {
    const int bx = blockIdx.x;
    const int tid = threadIdx.x;
    if (bx >= NT) {
        int i = (bx - NT) * 256 + tid;                    // 0..1048575 float4s
        const float* s; unsigned short* d;
        if (i < 786432) { s = wq; d = wqb; }
        else            { i -= 786432; s = wo; d = wob; }
        const float4 v = ((const float4*)s)[i];
        ((ushort4*)d)[i] = make_ushort4(f2bf(v.x), f2bf(v.y), f2bf(v.z), f2bf(v.w));
        return;
    }
    const float4 v = ((const float4*)(x + (size_t)bx * DD))[tid];
    float s = v.x + v.y + v.z + v.w;
    float ss = v.x*v.x + v.y*v.y + v.z*v.z + v.w*v.w;
    s = wred(s); ss = wred(ss);
    __shared__ float red[8];
    if ((tid & 63) == 0) { red[tid >> 6] = s; red[4 + (tid >> 6)] = ss; }
    __syncthreads();
    s  = red[0] + red[1] + red[2] + red[3];
    ss = red[4] + red[5] + red[6] + red[7];
    const float mu  = s * (1.0f / DD);
    const float inv = rsqrtf(ss * (1.0f / DD) - mu * mu + 1e-5f);
    const float4 wv = ((const float4*)w)[tid];
    const float4 bv = ((const float4*)b)[tid];
    *(ushort4*)(h + (size_t)bx * DD + tid * 4) = make_ushort4(
        f2bf((v.x - mu) * inv * wv.x + bv.x),
        f2bf((v.y - mu) * inv * wv.y + bv.y),
        f2bf((v.z - mu) * inv * wv.z + bv.z),
        f2bf((v.w - mu) * inv * wv.w + bv.w));
}

// -------------------- QKV GEMM: qk[t][2048] + V transposed to vt[B,H,DH,L] ----
__global__ __launch_bounds__(256) void gemm_qkv(
        const unsigned short* __restrict__ A, const unsigned short* __restrict__ B,
        unsigned short* __restrict__ qk, unsigned short* __restrict__ vt) {
    const int K = DD;
    __shared__ unsigned short As[128 * 32];
    __shared__ unsigned short Bs[128 * 32];
    const int tid = threadIdx.x;
    const int w = tid >> 6, lane = tid & 63;
    const int l15 = lane & 15, quad = lane >> 4;
    const int wr = w >> 1, wc = w & 1;
    const int m0 = blockIdx.y << 7, n0 = blockIdx.x << 7;

    const int srow = w * 32 + (lane >> 2);
    const int skel = (lane & 3) << 3;
    const unsigned short* gA = A + (size_t)(m0 + srow) * K + skel;
    const unsigned short* gB = B + (size_t)(n0 + srow) * K + skel;
    unsigned short* lA = &As[w * 1024];
    unsigned short* lB = &Bs[w * 1024];

    f32x4 acc[4][4];
#pragma unroll
    for (int i = 0; i < 4; i++)
#pragma unroll
        for (int j = 0; j < 4; j++) acc[i][j] = (f32x4){0.f, 0.f, 0.f, 0.f};

    for (int k0 = 0; k0 < K; k0 += 32) {
        gload16(gA + k0,                 lA);
        gload16(gA + k0 + (size_t)16*K,  lA + 512);
        gload16(gB + k0,                 lB);
        gload16(gB + k0 + (size_t)16*K,  lB + 512);
        __syncthreads();
        bf16x8 af[4], bg[4];
#pragma unroll
        for (int i = 0; i < 4; i++) {
            af[i] = *(const bf16x8*)&As[(wr*64 + i*16 + l15) * 32 + quad*8];
            bg[i] = *(const bf16x8*)&Bs[(wc*64 + i*16 + l15) * 32 + quad*8];
        }
#pragma unroll
        for (int i = 0; i < 4; i++)
#pragma unroll
            for (int j = 0; j < 4; j++)
                acc[i][j] = mfma16(af[i], bg[j], acc[i][j]);
        __syncthreads();
    }
    if (n0 < D2) {
#pragma unroll
        for (int i = 0; i < 4; i++) {
            const int mrow = m0 + wr*64 + i*16 + quad*4;
#pragma unroll
            for (int j = 0; j < 4; j++) {
                const int ncol = n0 + wc*64 + j*16 + l15;
#pragma unroll
                for (int r = 0; r < 4; r++)
                    qk[(size_t)(mrow + r) * D2 + ncol] = f2bf(acc[i][j][r]);
            }
        }
    } else {
#pragma unroll
        for (int i = 0; i < 4; i++) {
            const int mrow = m0 + wr*64 + i*16 + quad*4;
            const int bb = mrow >> 11, l = mrow & (LL - 1);
#pragma unroll
            for (int j = 0; j < 4; j++) {
                const int nv = n0 + wc*64 + j*16 + l15 - D2;
                const int hh = nv >> 6, dh = nv & 63;
                *(ushort4*)&vt[((size_t)(bb*HH + hh) * DHD + dh) * LL + l] =
                    make_ushort4(f2bf(acc[i][j][0]), f2bf(acc[i][j][1]),
                                 f2bf(acc[i][j][2]), f2bf(acc[i][j][3]));
            }
        }
    }
}

// -------------------- out-proj GEMM, 64x128 tile (2 blocks/CU) -----------------
__global__ __launch_bounds__(256) void gemm_out(
        const unsigned short* __restrict__ A, const unsigned short* __restrict__ B,
        float* __restrict__ C, int M, int N, int K) {
    __shared__ unsigned short As[64 * 32];
    __shared__ unsigned short Bs[128 * 32];
    const int tid = threadIdx.x;
    const int w = tid >> 6, lane = tid & 63;
    const int l15 = lane & 15, quad = lane >> 4;
    const int wr = w >> 1, wc = w & 1;
    const int m0 = blockIdx.y << 6, n0 = blockIdx.x << 7;
    const int skel = (lane & 3) << 3;
    const unsigned short* gA = A + (size_t)(m0 + w*16 + (lane >> 2)) * K + skel;
    const unsigned short* gB = B + (size_t)(n0 + w*32 + (lane >> 2)) * K + skel;
    unsigned short* lA = &As[w * 512];
    unsigned short* lB = &Bs[w * 1024];
    f32x4 acc[2][4];
#pragma unroll
    for (int i = 0; i < 2; i++)
#pragma unroll
        for (int j = 0; j < 4; j++) acc[i][j] = (f32x4){0.f, 0.f, 0.f, 0.f};
    for (int k0 = 0; k0 < K; k0 += 32) {
        gload16(gA + k0,                 lA);
        gload16(gB + k0,                 lB);
        gload16(gB + k0 + (size_t)16*K,  lB + 512);
        __syncthreads();
        bf16x8 af[2], bg[4];
#pragma unroll
        for (int i = 0; i < 2; i++)
            af[i] = *(const bf16x8*)&As[(wr*32 + i*16 + l15) * 32 + quad*8];
#pragma unroll
        for (int j = 0; j < 4; j++)
            bg[j] = *(const bf16x8*)&Bs[(wc*64 + j*16 + l15) * 32 + quad*8];
#pragma unroll
        for (int i = 0; i < 2; i++)
#pragma unroll
            for (int j = 0; j < 4; j++)
                acc[i][j] = mfma16(af[i], bg[j], acc[i][j]);
        __syncthreads();
    }
#pragma unroll
    for (int i = 0; i < 2; i++) {
        const int mrow = m0 + wr*32 + i*16 + quad*4;
#pragma unroll
        for (int j = 0; j < 4; j++) {
            const int ncol = n0 + wc*64 + j*16 + l15;
#pragma unroll
            for (int r = 0; r < 4; r++)
                C[(size_t)(mrow + r) * N + ncol] = acc[i][j][r];
        }
    }
}

// -------------------- Q/K LayerNorm + NeoX RoPE: qk -> qarr/karr [B,H,L,DH] ----
// Q pre-scaled by 0.125*log2(e): attention softmax runs in exp2 domain.
__global__ __launch_bounds__(256) void qk_rope_kernel(
        const unsigned short* __restrict__ qk,
        const float* __restrict__ qw, const float* __restrict__ kw,
        unsigned short* __restrict__ qarr, unsigned short* __restrict__ karr) {
    const int t = blockIdx.x;
    const int l = t & (LL - 1), b = t >> 11;
    const int tid = threadIdx.x;
    const unsigned short* base = qk + (size_t)t * D2;
    const ushort4 qu = *(const ushort4*)(base + tid * 4);
    const ushort4 ku = *(const ushort4*)(base + DD + tid * 4);
    const float q[4] = {bf2f(qu.x), bf2f(qu.y), bf2f(qu.z), bf2f(qu.w)};
    const float k[4] = {bf2f(ku.x), bf2f(ku.y), bf2f(ku.z), bf2f(ku.w)};
    float sq = q[0]+q[1]+q[2]+q[3], ssq = q[0]*q[0]+q[1]*q[1]+q[2]*q[2]+q[3]*q[3];
    float sk = k[0]+k[1]+k[2]+k[3], ssk = k[0]*k[0]+k[1]*k[1]+k[2]*k[2]+k[3]*k[3];
    sq = wred(sq); ssq = wred(ssq); sk = wred(sk); ssk = wred(ssk);
    __shared__ float red[16];
    __shared__ float qs[DD], ks[DD];
    const int wid = tid >> 6;
    if ((tid & 63) == 0) { red[wid] = sq; red[4+wid] = ssq; red[8+wid] = sk; red[12+wid] = ssk; }
    __syncthreads();
    sq = red[0]+red[1]+red[2]+red[3];    ssq = red[4]+red[5]+red[6]+red[7];
    sk = red[8]+red[9]+red[10]+red[11];  ssk = red[12]+red[13]+red[14]+red[15];
    const float muq = sq * (1.f/DD), invq = rsqrtf(ssq*(1.f/DD) - muq*muq + 1e-5f);
    const float muk = sk * (1.f/DD), invk = rsqrtf(ssk*(1.f/DD) - muk*muk + 1e-5f);
    const float4 qwv = ((const float4*)qw)[tid];
    const float4 kwv = ((const float4*)kw)[tid];
    const float qwa[4] = {qwv.x, qwv.y, qwv.z, qwv.w};
    const float kwa[4] = {kwv.x, kwv.y, kwv.z, kwv.w};
    float qn[4], kn[4];
#pragma unroll
    for (int e = 0; e < 4; e++) {
        qn[e] = (q[e] - muq) * invq * qwa[e];
        kn[e] = (k[e] - muk) * invk * kwa[e];
    }
    *(float4*)&qs[tid*4] = make_float4(qn[0], qn[1], qn[2], qn[3]);
    *(float4*)&ks[tid*4] = make_float4(kn[0], kn[1], kn[2], kn[3]);
    __syncthreads();
    const int d = tid * 4, j0 = d & 63;
    const bool first = (j0 < 32);
    const int pt = first ? (tid + 8) : (tid - 8);
    const float4 qp4 = *(const float4*)&qs[pt*4];
    const float4 kp4 = *(const float4*)&ks[pt*4];
    const float qb[4] = {qp4.x, qp4.y, qp4.z, qp4.w};
    const float kb[4] = {kp4.x, kp4.y, kp4.z, kp4.w};
    const float lf = (float)l;
    const float QS = 0.125f * 1.44269504088896340736f;   // 1/sqrt(DH) * log2(e)
    unsigned short oq[4], ok[4];
#pragma unroll
    for (int e = 0; e < 4; e++) {
        const float fi   = (float)((j0 & 31) + e);
        const float freq = expf(fi * (-0.28782313662425576f));   // 10000^(-i/32)
        const float ang  = lf * freq;
        const float c = cosf(ang), sn = sinf(ang);
        float vq, vk;
        if (first) { vq = qn[e]*c - qb[e]*sn; vk = kn[e]*c - kb[e]*sn; }
        else       { vq = qn[e]*c + qb[e]*sn; vk = kn[e]*c + kb[e]*sn; }
        oq[e] = f2bf(vq * QS);
        ok[e] = f2bf(vk);
    }
    const int hh = tid >> 4;
    const int dh = (tid * 4) & 63;
    const size_t ro = ((size_t)(b*HH + hh) * LL + l) * DHD + dh;
    *(ushort4*)(qarr + ro) = make_ushort4(oq[0], oq[1], oq[2], oq[3]);
    *(ushort4*)(karr + ro) = make_ushort4(ok[0], ok[1], ok[2], ok[3]);
}

// -------------------- MFMA flash attention, kv-split=4, fixed-shift softmax ----
// grid 2048: g=(bh,split) in [0,128), 16 qblks of one g share an XCD.
// Wave owns 32 q-rows; Pw single-buffered per wave (reused across qt).
__global__ __launch_bounds__(256, 4) void attn_kernel(
        const unsigned short* __restrict__ qarr,
        const unsigned short* __restrict__ karr,
        const unsigned short* __restrict__ vt,
        unsigned short* __restrict__ op0, unsigned short* __restrict__ op1,
        unsigned short* __restrict__ op2, unsigned short* __restrict__ op3,
        float* __restrict__ lpart) {          // [4][B*H][L]
    const int x = blockIdx.x;
    const int g  = (x & 7) | ((x >> 7) << 3);     // 0..127 = (bh, split)
    const int qblk = (x >> 3) & 15;
    const int s = g & 3, bh = g >> 2;
    const int b = bh >> 4, h = bh & 15;
    const int q0 = qblk << 7;
    const int kvbase = s * KVCH;
    const int tid = threadIdx.x, w = tid >> 6, lane = tid & 63;
    const int l15 = lane & 15, quad = lane >> 4;

    __shared__ unsigned short Ks[64 * 64];
    __shared__ unsigned short Vs[64 * 64];
    __shared__ unsigned short Pw[4][16][72];

    const unsigned short* kbase = karr + ((size_t)bh * LL + kvbase) * DHD;
    const unsigned short* vbase = vt   + (size_t)bh * DHD * LL + kvbase;

    bf16x8 qf[2][2];
    {
        const unsigned short* qp = qarr + ((size_t)bh*LL + q0 + w*32 + l15) * DHD + quad*8;
#pragma unroll
        for (int qt = 0; qt < 2; qt++)
#pragma unroll
            for (int c = 0; c < 2; c++)
                qf[qt][c] = *(const bf16x8*)(qp + qt*16*DHD + c*32);
    }

    bf16x8 ones;
#pragma unroll
    for (int i = 0; i < 8; i++) ones[i] = (__bf16)1.0f;

    const int r8 = lane >> 3, sc = lane & 7;
    f32x4 o[2][4], lacc[2];
#pragma unroll
    for (int qt = 0; qt < 2; qt++) {
        lacc[qt] = (f32x4){0.f, 0.f, 0.f, 0.f};
#pragma unroll
        for (int nt = 0; nt < 4; nt++) o[qt][nt] = (f32x4){0.f, 0.f, 0.f, 0.f};
    }

    // stage tile 0
#pragma unroll
    for (int rd = 0; rd < 2; rd++) {
        const int row = w*8 + rd*32 + r8;
        const int chunk = sc ^ (row & 7);
        gload16(kbase + (size_t)row * DHD + chunk*8, (char*)Ks + w*1024 + rd*4096);
        gload16(vbase + (size_t)row * LL + chunk*8,  (char*)Vs + w*1024 + rd*4096);
    }

    for (int kt = 0; kt < KVCH/64; kt++) {
        __syncthreads();                    // stage(kt) drained
        bf16x8 kf[4][2], vf[4][2];
#pragma unroll
        for (int t = 0; t < 4; t++)
#pragma unroll
            for (int c = 0; c < 2; c++) {
                const int slot = (quad + c*4) ^ (l15 & 7);
                kf[t][c] = *(const bf16x8*)&Ks[(t*16 + l15) * DHD + slot*8];
                vf[t][c] = *(const bf16x8*)&Vs[(t*16 + l15) * DHD + slot*8];
            }
        __syncthreads();                    // reads done; safe to overwrite
        if (kt + 1 < KVCH/64) {
#pragma unroll
            for (int rd = 0; rd < 2; rd++) {
                const int row = w*8 + rd*32 + r8;
                const int chunk = sc ^ (row & 7);
                gload16(kbase + ((size_t)((kt+1)*64 + row)) * DHD + chunk*8,
                        (char*)Ks + w*1024 + rd*4096);
                gload16(vbase + (size_t)row * LL + (kt+1)*64 + chunk*8,
                        (char*)Vs + w*1024 + rd*4096);
            }
        }

#pragma unroll
        for (int qt = 0; qt < 2; qt++) {
            // S^T = K.Q^T - 64 (fixed softmax shift via C-init)
            f32x4 st[4];
#pragma unroll
            for (int t = 0; t < 4; t++) {
                f32x4 z = (f32x4){-64.f, -64.f, -64.f, -64.f};
                z = mfma16(kf[t][0], qf[qt][0], z);
                z = mfma16(kf[t][1], qf[qt][1], z);
                st[t] = z;
            }
            // p = exp2(st); pack; wave-private LDS relayout (Pw reused per qt)
#pragma unroll
            for (int t = 0; t < 4; t++) {
                const float p0 = __builtin_amdgcn_exp2f(st[t][0]);
                const float p1 = __builtin_amdgcn_exp2f(st[t][1]);
                const float p2 = __builtin_amdgcn_exp2f(st[t][2]);
                const float p3 = __builtin_amdgcn_exp2f(st[t][3]);
                uint2 pk;
                pk.x = pack_bf2(p0, p1);
                pk.y = pack_bf2(p2, p3);
                *(uint2*)&Pw[w][l15][t*16 + quad*4] = pk;
            }
            const bf16x8 ap0 = *(const bf16x8*)&Pw[w][l15][quad*8];
            const bf16x8 ap1 = *(const bf16x8*)&Pw[w][l15][32 + quad*8];
            lacc[qt] = mfma16(ap0, ones, lacc[qt]);
            lacc[qt] = mfma16(ap1, ones, lacc[qt]);
#pragma unroll
            for (int nt = 0; nt < 4; nt++) {
                f32x4 t0 = o[qt][nt];
                t0 = mfma16(ap0, vf[nt][0], t0);
                t0 = mfma16(ap1, vf[nt][1], t0);
                o[qt][nt] = t0;
            }
        }
    }

    unsigned short* op = (s == 0) ? op0 : (s == 1) ? op1 : (s == 2) ? op2 : op3;
#pragma unroll
    for (int qt = 0; qt < 2; qt++) {
#pragma unroll
        for (int r = 0; r < 4; r++) {
            const int qrow = q0 + w*32 + qt*16 + quad*4 + r;
            const size_t token = (size_t)b * LL + qrow;
#pragma unroll
            for (int nt = 0; nt < 4; nt++)
                op[token * DD + h*DHD + nt*16 + l15] = f2bf(o[qt][nt][r]);
        }
        if (l15 == 0) {
#pragma unroll
            for (int r = 0; r < 4; r++)
                lpart[((size_t)s * BB*HH + bh) * LL + q0 + w*32 + qt*16 + quad*4 + r] =
                    lacc[qt][r];
        }
    }
}

// -------------------- combine kv-split partials -> ctx bf16 --------------------
__global__ __launch_bounds__(256) void combine_kernel(
        const unsigned short* __restrict__ op0, const unsigned short* __restrict__ op1,
        const unsigned short* __restrict__ op2, const unsigned short* __restrict__ op3,
        const float* __restrict__ lpart, unsigned short* __restrict__ ctx) {
    const int token = blockIdx.x;
    const int tid = threadIdx.x;
    const int b = token >> 11, l = token & (LL - 1);
    const int h = tid >> 4;
    const size_t idx = (size_t)token * DD + tid * 4;
    const ushort4 a0 = *(const ushort4*)(op0 + idx);
    const ushort4 a1 = *(const ushort4*)(op1 + idx);
    const ushort4 a2 = *(const ushort4*)(op2 + idx);
    const ushort4 a3 = *(const ushort4*)(op3 + idx);
    const size_t lbase = (size_t)(b*HH + h) * LL + l;
    const float lsum = lpart[lbase] + lpart[(size_t)BB*HH*LL + lbase]
                     + lpart[2*(size_t)BB*HH*LL + lbase] + lpart[3*(size_t)BB*HH*LL + lbase];
    const float inv = 1.0f / lsum;
    *(ushort4*)(ctx + idx) = make_ushort4(
        f2bf((bf2f(a0.x) + bf2f(a1.x) + bf2f(a2.x) + bf2f(a3.x)) * inv),
        f2bf((bf2f(a0.y) + bf2f(a1.y) + bf2f(a2.y) + bf2f(a3.y)) * inv),
        f2bf((bf2f(a0.z) + bf2f(a1.z) + bf2f(a2.z) + bf2f(a3.z)) * inv),
        f2bf((bf2f(a0.w) + bf2f(a1.w) + bf2f(a2.w) + bf2f(a3.w)) * inv));
}

extern "C" void kernel_launch(void* const* d_in, const int* in_sizes, int n_in,
                              void* d_out, int out_size, void* d_ws, size_t ws_size,
                              hipStream_t stream) {
    const float* x      = (const float*)d_in[0];
    const float* ln_w   = (const float*)d_in[1];
    const float* ln_b   = (const float*)d_in[2];
    const float* w_qkv  = (const float*)d_in[3];
    const float* q_ln_w = (const float*)d_in[4];
    const float* k_ln_w = (const float*)d_in[5];
    const float* w_out  = (const float*)d_in[6];
    float* out = (float*)d_out;

    // workspace map (64 MB), lifetime-aliased:
    //  [0,8M)   h bf16 -> karr (rope)
    //  [8,24M)  qk bf16 -> opart s0 [8,16) / s1 [16,24) (attn; qk dead after rope)
    //  [24,32M) vt bf16 [B,H,DH,L]
    //  [32,40M) qarr bf16 -> ctx (combine; qarr dead after attn)
    //  [40,56M) opart s2 [40,48) / s3 [48,56)
    //  [56,62M) wqb -> lpart fp32 1MB (attn; wqb dead after gemm_qkv)
    //  [62,64M) wob
    char* ws = (char*)d_ws;
    unsigned short* hb    = (unsigned short*)ws;
    unsigned short* karr  = (unsigned short*)ws;
    unsigned short* qk    = (unsigned short*)(ws + ((size_t)8  << 20));
    unsigned short* op0   = (unsigned short*)(ws + ((size_t)8  << 20));
    unsigned short* op1   = (unsigned short*)(ws + ((size_t)16 << 20));
    unsigned short* vtp   = (unsigned short*)(ws + ((size_t)24 << 20));
    unsigned short* qarr  = (unsigned short*)(ws + ((size_t)32 << 20));
    unsigned short* ctxb  = (unsigned short*)(ws + ((size_t)32 << 20));
    unsigned short* op2   = (unsigned short*)(ws + ((size_t)40 << 20));
    unsigned short* op3   = (unsigned short*)(ws + ((size_t)48 << 20));
    unsigned short* wqb   = (unsigned short*)(ws + ((size_t)56 << 20));
    float*          lpart = (float*)(ws + ((size_t)56 << 20));
    unsigned short* wob   = (unsigned short*)(ws + ((size_t)62 << 20));

    ln_cvt_kernel<<<NT + 4096, 256, 0, stream>>>(x, ln_w, ln_b, hb,
                                                 w_qkv, wqb, w_out, wob);
    gemm_qkv<<<dim3(D3/128, NT/128), 256, 0, stream>>>(hb, wqb, qk, vtp);
    qk_rope_kernel<<<NT, 256, 0, stream>>>(qk, q_ln_w, k_ln_w, qarr, karr);
    attn_kernel<<<2048, 256, 0, stream>>>(qarr, karr, vtp, op0, op1, op2, op3, lpart);
    combine_kernel<<<NT, 256, 0, stream>>>(op0, op1, op2, op3, lpart, ctxb);
    gemm_out<<<dim3(DD/128, NT/64), 256, 0, stream>>>(ctxb, wob, out, NT, DD, DD);
}

// Round 6
// 249.105 us; speedup vs baseline: 1.1192x; 1.1192x over previous
//
#include <hip/hip_runtime.h>
#include <math.h>

#define BB 2
#define LL 2048
#define DD 1024
#define HH 16
#define DHD 64
#define NT (BB*LL)
#define D3 (3*DD)
#define D2 (2*DD)

typedef __bf16 bf16x8 __attribute__((ext_vector_type(8)));
typedef float  f32x4  __attribute__((ext_vector_type(4)));

__device__ __forceinline__ f32x4 mfma16(bf16x8 a, bf16x8 b, f32x4 c) {
    return __builtin_amdgcn_mfma_f32_16x16x32_bf16(a, b, c, 0, 0, 0);
}

__device__ __forceinline__ unsigned short f2bf(float f) {
    unsigned int u = __float_as_uint(f);
    u = (u + 0x7FFFu + ((u >> 16) & 1u)) >> 16;
    return (unsigned short)u;
}
__device__ __forceinline__ float bf2f(unsigned short s) {
    return __uint_as_float(((unsigned int)s) << 16);
}

__device__ __forceinline__ void gload16(const void* g, void* l) {
    __builtin_amdgcn_global_load_lds(
        (const __attribute__((address_space(1))) void*)g,
        (__attribute__((address_space(3))) void*)l, 16, 0, 0);
}

__device__ __forceinline__ float wred(float v) {
#pragma unroll
    for (int off = 32; off > 0; off >>= 1) v += __shfl_down(v, off, 64);
    return v;
}

// pack two positive fp32 -> bf16 pair (round-half-up) in 3 VALU ops
__device__ __forceinline__ unsigned int pack_bf2(float p0, float p1) {
    const unsigned int u0 = __float_as_uint(p0) + 0x8000u;
    const unsigned int u1 = __float_as_uint(p1) + 0x8000u;
    return __builtin_amdgcn_perm(u1, u0, 0x07060302u);  // [u1.hi16 : u0.hi16]
}

// -------------------- fused LayerNorm (blocks 0..NT-1) + weight cvt ----------
__global__ __launch_bounds__(256) void ln_cvt_kernel(
        const float* __restrict__ x, const float* __restrict__ w,
        const float* __restrict__ b, unsigned short* __restrict__ h,
        const float* __restrict__ wq, unsigned short* __restrict__ wqb,
        const float* __restrict__ wo, unsigned short* __restrict__ wob) {
    const int bx = blockIdx.x;
    const int tid = threadIdx.x;
    if (bx >= NT) {
        int i = (bx - NT) * 256 + tid;                    // 0..1048575 float4s
        const float* s; unsigned short* d;
        if (i < 786432) { s = wq; d = wqb; }
        else            { i -= 786432; s = wo; d = wob; }
        const float4 v = ((const float4*)s)[i];
        ((ushort4*)d)[i] = make_ushort4(f2bf(v.x), f2bf(v.y), f2bf(v.z), f2bf(v.w));
        return;
    }
    const float4 v = ((const float4*)(x + (size_t)bx * DD))[tid];
    float s = v.x + v.y + v.z + v.w;
    float ss = v.x*v.x + v.y*v.y + v.z*v.z + v.w*v.w;
    s = wred(s); ss = wred(ss);
    __shared__ float red[8];
    if ((tid & 63) == 0) { red[tid >> 6] = s; red[4 + (tid >> 6)] = ss; }
    __syncthreads();
    s  = red[0] + red[1] + red[2] + red[3];
    ss = red[4] + red[5] + red[6] + red[7];
    const float mu  = s * (1.0f / DD);
    const float inv = rsqrtf(ss * (1.0f / DD) - mu * mu + 1e-5f);
    const float4 wv = ((const float4*)w)[tid];
    const float4 bv = ((const float4*)b)[tid];
    *(ushort4*)(h + (size_t)bx * DD + tid * 4) = make_ushort4(
        f2bf((v.x - mu) * inv * wv.x + bv.x),
        f2bf((v.y - mu) * inv * wv.y + bv.y),
        f2bf((v.z - mu) * inv * wv.z + bv.z),
        f2bf((v.w - mu) * inv * wv.w + bv.w));
}

// -------------------- QKV GEMM: qk[t][2048] + V transposed to vt[B,H,DH,L] ----
__global__ __launch_bounds__(256) void gemm_qkv(
        const unsigned short* __restrict__ A, const unsigned short* __restrict__ B,
        unsigned short* __restrict__ qk, unsigned short* __restrict__ vt) {
    const int K = DD;
    __shared__ unsigned short As[128 * 32];
    __shared__ unsigned short Bs[128 * 32];
    const int tid = threadIdx.x;
    const int w = tid >> 6, lane = tid & 63;
    const int l15 = lane & 15, quad = lane >> 4;
    const int wr = w >> 1, wc = w & 1;
    const int m0 = blockIdx.y << 7, n0 = blockIdx.x << 7;

    const int srow = w * 32 + (lane >> 2);
    const int skel = (lane & 3) << 3;
    const unsigned short* gA = A + (size_t)(m0 + srow) * K + skel;
    const unsigned short* gB = B + (size_t)(n0 + srow) * K + skel;
    unsigned short* lA = &As[w * 1024];
    unsigned short* lB = &Bs[w * 1024];

    f32x4 acc[4][4];
#pragma unroll
    for (int i = 0; i < 4; i++)
#pragma unroll
        for (int j = 0; j < 4; j++) acc[i][j] = (f32x4){0.f, 0.f, 0.f, 0.f};

    for (int k0 = 0; k0 < K; k0 += 32) {
        gload16(gA + k0,                 lA);
        gload16(gA + k0 + (size_t)16*K,  lA + 512);
        gload16(gB + k0,                 lB);
        gload16(gB + k0 + (size_t)16*K,  lB + 512);
        __syncthreads();
        bf16x8 af[4], bg[4];
#pragma unroll
        for (int i = 0; i < 4; i++) {
            af[i] = *(const bf16x8*)&As[(wr*64 + i*16 + l15) * 32 + quad*8];
            bg[i] = *(const bf16x8*)&Bs[(wc*64 + i*16 + l15) * 32 + quad*8];
        }
#pragma unroll
        for (int i = 0; i < 4; i++)
#pragma unroll
            for (int j = 0; j < 4; j++)
                acc[i][j] = mfma16(af[i], bg[j], acc[i][j]);
        __syncthreads();
    }
    if (n0 < D2) {
#pragma unroll
        for (int i = 0; i < 4; i++) {
            const int mrow = m0 + wr*64 + i*16 + quad*4;
#pragma unroll
            for (int j = 0; j < 4; j++) {
                const int ncol = n0 + wc*64 + j*16 + l15;
#pragma unroll
                for (int r = 0; r < 4; r++)
                    qk[(size_t)(mrow + r) * D2 + ncol] = f2bf(acc[i][j][r]);
            }
        }
    } else {
#pragma unroll
        for (int i = 0; i < 4; i++) {
            const int mrow = m0 + wr*64 + i*16 + quad*4;
            const int bb = mrow >> 11, l = mrow & (LL - 1);
#pragma unroll
            for (int j = 0; j < 4; j++) {
                const int nv = n0 + wc*64 + j*16 + l15 - D2;
                const int hh = nv >> 6, dh = nv & 63;
                *(ushort4*)&vt[((size_t)(bb*HH + hh) * DHD + dh) * LL + l] =
                    make_ushort4(f2bf(acc[i][j][0]), f2bf(acc[i][j][1]),
                                 f2bf(acc[i][j][2]), f2bf(acc[i][j][3]));
            }
        }
    }
}

// -------------------- out-proj GEMM, 64x128 tile (2+ blocks/CU) ----------------
__global__ __launch_bounds__(256) void gemm_out(
        const unsigned short* __restrict__ A, const unsigned short* __restrict__ B,
        float* __restrict__ C, int M, int N, int K) {
    __shared__ unsigned short As[64 * 32];
    __shared__ unsigned short Bs[128 * 32];
    const int tid = threadIdx.x;
    const int w = tid >> 6, lane = tid & 63;
    const int l15 = lane & 15, quad = lane >> 4;
    const int wr = w >> 1, wc = w & 1;
    const int m0 = blockIdx.y << 6, n0 = blockIdx.x << 7;
    const int skel = (lane & 3) << 3;
    const unsigned short* gA = A + (size_t)(m0 + w*16 + (lane >> 2)) * K + skel;
    const unsigned short* gB = B + (size_t)(n0 + w*32 + (lane >> 2)) * K + skel;
    unsigned short* lA = &As[w * 512];
    unsigned short* lB = &Bs[w * 1024];
    f32x4 acc[2][4];
#pragma unroll
    for (int i = 0; i < 2; i++)
#pragma unroll
        for (int j = 0; j < 4; j++) acc[i][j] = (f32x4){0.f, 0.f, 0.f, 0.f};
    for (int k0 = 0; k0 < K; k0 += 32) {
        gload16(gA + k0,                 lA);
        gload16(gB + k0,                 lB);
        gload16(gB + k0 + (size_t)16*K,  lB + 512);
        __syncthreads();
        bf16x8 af[2], bg[4];
#pragma unroll
        for (int i = 0; i < 2; i++)
            af[i] = *(const bf16x8*)&As[(wr*32 + i*16 + l15) * 32 + quad*8];
#pragma unroll
        for (int j = 0; j < 4; j++)
            bg[j] = *(const bf16x8*)&Bs[(wc*64 + j*16 + l15) * 32 + quad*8];
#pragma unroll
        for (int i = 0; i < 2; i++)
#pragma unroll
            for (int j = 0; j < 4; j++)
                acc[i][j] = mfma16(af[i], bg[j], acc[i][j]);
        __syncthreads();
    }
#pragma unroll
    for (int i = 0; i < 2; i++) {
        const int mrow = m0 + wr*32 + i*16 + quad*4;
#pragma unroll
        for (int j = 0; j < 4; j++) {
            const int ncol = n0 + wc*64 + j*16 + l15;
#pragma unroll
            for (int r = 0; r < 4; r++)
                C[(size_t)(mrow + r) * N + ncol] = acc[i][j][r];
        }
    }
}

// -------------------- Q/K LayerNorm + NeoX RoPE: qk -> qarr/karr [B,H,L,DH] ----
// Fast transcendentals: freq via exp2, sin/cos via HW v_sin/v_cos (revolutions).
// Q pre-scaled by 0.125*log2(e): attention softmax runs in exp2 domain.
__global__ __launch_bounds__(256) void qk_rope_kernel(
        const unsigned short* __restrict__ qk,
        const float* __restrict__ qw, const float* __restrict__ kw,
        unsigned short* __restrict__ qarr, unsigned short* __restrict__ karr) {
    const int t = blockIdx.x;
    const int l = t & (LL - 1), b = t >> 11;
    const int tid = threadIdx.x;
    const unsigned short* base = qk + (size_t)t * D2;
    const ushort4 qu = *(const ushort4*)(base + tid * 4);
    const ushort4 ku = *(const ushort4*)(base + DD + tid * 4);
    const float q[4] = {bf2f(qu.x), bf2f(qu.y), bf2f(qu.z), bf2f(qu.w)};
    const float k[4] = {bf2f(ku.x), bf2f(ku.y), bf2f(ku.z), bf2f(ku.w)};
    float sq = q[0]+q[1]+q[2]+q[3], ssq = q[0]*q[0]+q[1]*q[1]+q[2]*q[2]+q[3]*q[3];
    float sk = k[0]+k[1]+k[2]+k[3], ssk = k[0]*k[0]+k[1]*k[1]+k[2]*k[2]+k[3]*k[3];
    sq = wred(sq); ssq = wred(ssq); sk = wred(sk); ssk = wred(ssk);
    __shared__ float red[16];
    __shared__ float qs[DD], ks[DD];
    const int wid = tid >> 6;
    if ((tid & 63) == 0) { red[wid] = sq; red[4+wid] = ssq; red[8+wid] = sk; red[12+wid] = ssk; }
    __syncthreads();
    sq = red[0]+red[1]+red[2]+red[3];    ssq = red[4]+red[5]+red[6]+red[7];
    sk = red[8]+red[9]+red[10]+red[11];  ssk = red[12]+red[13]+red[14]+red[15];
    const float muq = sq * (1.f/DD), invq = rsqrtf(ssq*(1.f/DD) - muq*muq + 1e-5f);
    const float muk = sk * (1.f/DD), invk = rsqrtf(ssk*(1.f/DD) - muk*muk + 1e-5f);
    const float4 qwv = ((const float4*)qw)[tid];
    const float4 kwv = ((const float4*)kw)[tid];
    const float qwa[4] = {qwv.x, qwv.y, qwv.z, qwv.w};
    const float kwa[4] = {kwv.x, kwv.y, kwv.z, kwv.w};
    float qn[4], kn[4];
#pragma unroll
    for (int e = 0; e < 4; e++) {
        qn[e] = (q[e] - muq) * invq * qwa[e];
        kn[e] = (k[e] - muk) * invk * kwa[e];
    }
    *(float4*)&qs[tid*4] = make_float4(qn[0], qn[1], qn[2], qn[3]);
    *(float4*)&ks[tid*4] = make_float4(kn[0], kn[1], kn[2], kn[3]);
    __syncthreads();
    const int d = tid * 4, j0 = d & 63;
    const bool first = (j0 < 32);
    const int pt = first ? (tid + 8) : (tid - 8);
    const float4 qp4 = *(const float4*)&qs[pt*4];
    const float4 kp4 = *(const float4*)&ks[pt*4];
    const float qb[4] = {qp4.x, qp4.y, qp4.z, qp4.w};
    const float kb[4] = {kp4.x, kp4.y, kp4.z, kp4.w};
    const float lf = (float)l;
    const float QS = 0.125f * 1.44269504088896340736f;   // 1/sqrt(DH) * log2(e)
    unsigned short oq[4], ok[4];
#pragma unroll
    for (int e = 0; e < 4; e++) {
        const float fi   = (float)((j0 & 31) + e);
        // 10000^(-fi/32)/(2pi) = exp2(-fi*log2(1e4)/32) * (1/2pi)
        const float frev = __builtin_amdgcn_exp2f(fi * -0.41524101186092029f)
                         * 0.15915494309189535f;
        float rev = lf * frev;
        rev -= floorf(rev);
        const float sn = __builtin_amdgcn_sinf(rev);   // sin(2*pi*rev)
        const float c  = __builtin_amdgcn_cosf(rev);   // cos(2*pi*rev)
        float vq, vk;
        if (first) { vq = qn[e]*c - qb[e]*sn; vk = kn[e]*c - kb[e]*sn; }
        else       { vq = qn[e]*c + qb[e]*sn; vk = kn[e]*c + kb[e]*sn; }
        oq[e] = f2bf(vq * QS);
        ok[e] = f2bf(vk);
    }
    const int hh = tid >> 4;
    const int dh = (tid * 4) & 63;
    const size_t ro = ((size_t)(b*HH + hh) * LL + l) * DHD + dh;
    *(ushort4*)(qarr + ro) = make_ushort4(oq[0], oq[1], oq[2], oq[3]);
    *(ushort4*)(karr + ro) = make_ushort4(ok[0], ok[1], ok[2], ok[3]);
}

// -------------------- MFMA flash attention, IN-BLOCK kv-split ------------------
// grid 1024 (XCD-swizzled): block = (bh, 64 q-rows). 4 waves: wave w has
// q-row-half wr=w&1 (rows wr*32..+32) and kv-half h=w>>1 (kv [h*1024,+1024)).
// Fixed-shift exp2 softmax (no partials to HBM); halves merged in LDS at the
// end, then divided by l and stored as coalesced 128B row segments.
__global__ __launch_bounds__(256, 4) void attn_kernel(
        const unsigned short* __restrict__ qarr,
        const unsigned short* __restrict__ karr,
        const unsigned short* __restrict__ vt,
        unsigned short* __restrict__ ctxb) {
    const int x = blockIdx.x;
    const int bh = (x & 7) | ((x >> 8) << 3);   // 32 qblks of one head per XCD
    const int qblk = (x >> 3) & 31;
    const int b = bh >> 4, hh = bh & 15;
    const int q0 = qblk << 6;
    const int tid = threadIdx.x, w = tid >> 6, lane = tid & 63;
    const int l15 = lane & 15, quad = lane >> 4;
    const int h  = w >> 1;          // kv half
    const int wr = w & 1;           // q-row half

    __shared__ union {
        struct {
            unsigned short Ks[2 * 32 * 64];   // [half][kvrow 32][dh 64] (chunk-xor)
            unsigned short Vs[2 * 64 * 32];   // [half][dh 64][kv 32] (chunk-xor)
            unsigned short Pw[4][16][40];     // per-wave P relayout
        } m;
        struct {
            float red[64][64];                // [token][dh] fp32 half-1 dump
            float lred[64];                   // half-1 l
            unsigned short red_bf[64][72];    // final bf16, for coalesced store
        } e;
    } sm;

    const unsigned short* kbase = karr + ((size_t)bh * LL + h * 1024) * DHD;
    const unsigned short* vbase = vt   + (size_t)bh * DHD * LL + h * 1024;

    // Q frags (B-operand), persistent: rows q0 + wr*32 .. +32
    bf16x8 qf[2][2];
    {
        const unsigned short* qp = qarr + ((size_t)bh*LL + q0 + wr*32 + l15) * DHD + quad*8;
#pragma unroll
        for (int qt = 0; qt < 2; qt++)
#pragma unroll
            for (int c = 0; c < 2; c++)
                qf[qt][c] = *(const bf16x8*)(qp + qt*16*DHD + c*32);
    }

    bf16x8 ones;
#pragma unroll
    for (int i = 0; i < 8; i++) ones[i] = (__bf16)1.0f;

    const int p = w & 1;   // staging part within half (happens to equal wr)
    f32x4 o[2][4], lacc[2];
#pragma unroll
    for (int qt = 0; qt < 2; qt++) {
        lacc[qt] = (f32x4){0.f, 0.f, 0.f, 0.f};
#pragma unroll
        for (int nt = 0; nt < 4; nt++) o[qt][nt] = (f32x4){0.f, 0.f, 0.f, 0.f};
    }

    // staging lambda-ish: wave (h,p) stages K rows p*16..+16 (2 instrs),
    // V dh-rows p*32..+32 (2 instrs) of its own half.
    const int kr8 = lane >> 3, kc = lane & 7;         // K: 8 rows x 8 chunks
    const int vr4 = lane >> 2, vc = lane & 3;         // V: 16 rows x 4 chunks
#define STAGE(KT)                                                                   \
    {                                                                               \
        const int kt_ = (KT);                                                       \
        _Pragma("unroll")                                                           \
        for (int rd = 0; rd < 2; rd++) {                                            \
            const int row = p*16 + rd*8 + kr8;                                      \
            gload16(kbase + (size_t)(kt_*32 + row) * DHD + (kc ^ kr8) * 8,          \
                    &sm.m.Ks[h*2048 + (p*16 + rd*8) * 64]);                         \
        }                                                                           \
        _Pragma("unroll")                                                           \
        for (int rv = 0; rv < 2; rv++) {                                            \
            const int dhrow = p*32 + rv*16 + vr4;                                   \
            gload16(vbase + (size_t)dhrow * LL + kt_*32 + (vc ^ (vr4 & 3)) * 8,     \
                    &sm.m.Vs[h*2048 + (p*32 + rv*16) * 32]);                        \
        }                                                                           \
    }

    STAGE(0);

    for (int kt = 0; kt < 32; kt++) {
        __syncthreads();                    // stage(kt) drained
        bf16x8 kf[2][2], vf[4];
#pragma unroll
        for (int t = 0; t < 2; t++)
#pragma unroll
            for (int c = 0; c < 2; c++) {
                const int slot = (quad + c*4) ^ (l15 & 7);
                kf[t][c] = *(const bf16x8*)&sm.m.Ks[h*2048 + (t*16 + l15) * 64 + slot*8];
            }
#pragma unroll
        for (int nt = 0; nt < 4; nt++) {
            const int slot = quad ^ (l15 & 3);
            vf[nt] = *(const bf16x8*)&sm.m.Vs[h*2048 + (nt*16 + l15) * 32 + slot*8];
        }
        __syncthreads();                    // reads done; safe to overwrite
        if (kt + 1 < 32) STAGE(kt + 1);

#pragma unroll
        for (int qt = 0; qt < 2; qt++) {
            // S^T = K.Q^T - 64 (fixed softmax shift via C-init)
            f32x4 st[2];
#pragma unroll
            for (int t = 0; t < 2; t++) {
                f32x4 z = (f32x4){-64.f, -64.f, -64.f, -64.f};
                z = mfma16(kf[t][0], qf[qt][0], z);
                z = mfma16(kf[t][1], qf[qt][1], z);
                st[t] = z;
            }
#pragma unroll
            for (int t = 0; t < 2; t++) {
                const float p0 = __builtin_amdgcn_exp2f(st[t][0]);
                const float p1 = __builtin_amdgcn_exp2f(st[t][1]);
                const float p2 = __builtin_amdgcn_exp2f(st[t][2]);
                const float p3 = __builtin_amdgcn_exp2f(st[t][3]);
                uint2 pk;
                pk.x = pack_bf2(p0, p1);
                pk.y = pack_bf2(p2, p3);
                *(uint2*)&sm.m.Pw[w][l15][t*16 + quad*4] = pk;
            }
            const bf16x8 ap = *(const bf16x8*)&sm.m.Pw[w][l15][quad*8];
            lacc[qt] = mfma16(ap, ones, lacc[qt]);
#pragma unroll
            for (int nt = 0; nt < 4; nt++)
                o[qt][nt] = mfma16(ap, vf[nt], o[qt][nt]);
        }
    }
#undef STAGE

    // ---- in-block merge of the two kv halves ----
    __syncthreads();                        // all LDS (Ks/Vs/Pw) dead
    if (h == 1) {
#pragma unroll
        for (int qt = 0; qt < 2; qt++) {
#pragma unroll
            for (int nt = 0; nt < 4; nt++)
#pragma unroll
                for (int r = 0; r < 4; r++)
                    sm.e.red[wr*32 + qt*16 + quad*4 + r][nt*16 + l15] = o[qt][nt][r];
            if (l15 == 0)
#pragma unroll
                for (int r = 0; r < 4; r++)
                    sm.e.lred[wr*32 + qt*16 + quad*4 + r] = lacc[qt][r];
        }
    }
    __syncthreads();
    if (h == 0) {
#pragma unroll
        for (int qt = 0; qt < 2; qt++) {
            float inv[4];
#pragma unroll
            for (int r = 0; r < 4; r++)
                inv[r] = 1.0f / (lacc[qt][r] + sm.e.lred[wr*32 + qt*16 + quad*4 + r]);
#pragma unroll
            for (int nt = 0; nt < 4; nt++)
#pragma unroll
                for (int r = 0; r < 4; r++) {
                    const int tok = wr*32 + qt*16 + quad*4 + r;
                    const float v = (o[qt][nt][r] + sm.e.red[tok][nt*16 + l15]) * inv[r];
                    sm.e.red_bf[tok][nt*16 + l15] = f2bf(v);
                }
        }
    }
    __syncthreads();
    // coalesced store: 64 tokens x 128B segments
#pragma unroll
    for (int i = 0; i < 2; i++) {
        const int idx = tid + 256*i;
        const int token = idx >> 3, ch = idx & 7;
        const uint4 vdat = *(const uint4*)&sm.e.red_bf[token][ch*8];
        *(uint4*)&ctxb[(size_t)(b*LL + q0 + token) * DD + hh*DHD + ch*8] = vdat;
    }
}

extern "C" void kernel_launch(void* const* d_in, const int* in_sizes, int n_in,
                              void* d_out, int out_size, void* d_ws, size_t ws_size,
                              hipStream_t stream) {
    const float* x      = (const float*)d_in[0];
    const float* ln_w   = (const float*)d_in[1];
    const float* ln_b   = (const float*)d_in[2];
    const float* w_qkv  = (const float*)d_in[3];
    const float* q_ln_w = (const float*)d_in[4];
    const float* k_ln_w = (const float*)d_in[5];
    const float* w_out  = (const float*)d_in[6];
    float* out = (float*)d_out;

    // workspace map (48 MB), lifetime-aliased:
    //  [0,8M)   h bf16 -> karr [B,H,L,DH] (rope; h dead after gemm_qkv)
    //  [8,24M)  qk bf16 [t][2048] -> ctx bf16 (attn; qk dead after rope)
    //  [24,32M) vt bf16 [B,H,DH,L]
    //  [32,40M) qarr bf16 [B,H,L,DH]
    //  [40,46M) wqb ; [46,48M) wob
    char* ws = (char*)d_ws;
    unsigned short* hb    = (unsigned short*)ws;
    unsigned short* karr  = (unsigned short*)ws;
    unsigned short* qk    = (unsigned short*)(ws + ((size_t)8  << 20));
    unsigned short* ctxb  = (unsigned short*)(ws + ((size_t)8  << 20));
    unsigned short* vtp   = (unsigned short*)(ws + ((size_t)24 << 20));
    unsigned short* qarr  = (unsigned short*)(ws + ((size_t)32 << 20));
    unsigned short* wqb   = (unsigned short*)(ws + ((size_t)40 << 20));
    unsigned short* wob   = (unsigned short*)(ws + ((size_t)46 << 20));

    ln_cvt_kernel<<<NT + 4096, 256, 0, stream>>>(x, ln_w, ln_b, hb,
                                                 w_qkv, wqb, w_out, wob);
    gemm_qkv<<<dim3(D3/128, NT/128), 256, 0, stream>>>(hb, wqb, qk, vtp);
    qk_rope_kernel<<<NT, 256, 0, stream>>>(qk, q_ln_w, k_ln_w, qarr, karr);
    attn_kernel<<<1024, 256, 0, stream>>>(qarr, karr, vtp, ctxb);
    gemm_out<<<dim3(DD/128, NT/64), 256, 0, stream>>>(ctxb, wob, out, NT, DD, DD);
}

// Round 7
// 228.445 us; speedup vs baseline: 1.2204x; 1.0904x over previous
//
#include <hip/hip_runtime.h>
#include <math.h>

#define BB 2
#define LL 2048
#define DD 1024
#define HH 16
#define DHD 64
#define NT (BB*LL)
#define D3 (3*DD)
#define D2 (2*DD)

typedef __bf16 bf16x8 __attribute__((ext_vector_type(8)));
typedef float  f32x4  __attribute__((ext_vector_type(4)));

__device__ __forceinline__ f32x4 mfma16(bf16x8 a, bf16x8 b, f32x4 c) {
    return __builtin_amdgcn_mfma_f32_16x16x32_bf16(a, b, c, 0, 0, 0);
}

__device__ __forceinline__ unsigned short f2bf(float f) {
    unsigned int u = __float_as_uint(f);
    u = (u + 0x7FFFu + ((u >> 16) & 1u)) >> 16;
    return (unsigned short)u;
}
__device__ __forceinline__ float bf2f(unsigned short s) {
    return __uint_as_float(((unsigned int)s) << 16);
}

__device__ __forceinline__ void gload16(const void* g, void* l) {
    __builtin_amdgcn_global_load_lds(
        (const __attribute__((address_space(1))) void*)g,
        (__attribute__((address_space(3))) void*)l, 16, 0, 0);
}

__device__ __forceinline__ float wred(float v) {
#pragma unroll
    for (int off = 32; off > 0; off >>= 1) v += __shfl_down(v, off, 64);
    return v;
}

// pack two positive fp32 -> bf16 pair (round-half-up) in 3 VALU ops
__device__ __forceinline__ unsigned int pack_bf2(float p0, float p1) {
    const unsigned int u0 = __float_as_uint(p0) + 0x8000u;
    const unsigned int u1 = __float_as_uint(p1) + 0x8000u;
    return __builtin_amdgcn_perm(u1, u0, 0x07060302u);  // [u1.hi16 : u0.hi16]
}

// -------------------- fused LayerNorm (blocks 0..NT-1) + weight cvt ----------
__global__ __launch_bounds__(256) void ln_cvt_kernel(
        const float* __restrict__ x, const float* __restrict__ w,
        const float* __restrict__ b, unsigned short* __restrict__ h,
        const float* __restrict__ wq, unsigned short* __restrict__ wqb,
        const float* __restrict__ wo, unsigned short* __restrict__ wob) {
    const int bx = blockIdx.x;
    const int tid = threadIdx.x;
    if (bx >= NT) {
        int i = (bx - NT) * 256 + tid;                    // 0..1048575 float4s
        const float* s; unsigned short* d;
        if (i < 786432) { s = wq; d = wqb; }
        else            { i -= 786432; s = wo; d = wob; }
        const float4 v = ((const float4*)s)[i];
        ((ushort4*)d)[i] = make_ushort4(f2bf(v.x), f2bf(v.y), f2bf(v.z), f2bf(v.w));
        return;
    }
    const float4 v = ((const float4*)(x + (size_t)bx * DD))[tid];
    float s = v.x + v.y + v.z + v.w;
    float ss = v.x*v.x + v.y*v.y + v.z*v.z + v.w*v.w;
    s = wred(s); ss = wred(ss);
    __shared__ float red[8];
    if ((tid & 63) == 0) { red[tid >> 6] = s; red[4 + (tid >> 6)] = ss; }
    __syncthreads();
    s  = red[0] + red[1] + red[2] + red[3];
    ss = red[4] + red[5] + red[6] + red[7];
    const float mu  = s * (1.0f / DD);
    const float inv = rsqrtf(ss * (1.0f / DD) - mu * mu + 1e-5f);
    const float4 wv = ((const float4*)w)[tid];
    const float4 bv = ((const float4*)b)[tid];
    *(ushort4*)(h + (size_t)bx * DD + tid * 4) = make_ushort4(
        f2bf((v.x - mu) * inv * wv.x + bv.x),
        f2bf((v.y - mu) * inv * wv.y + bv.y),
        f2bf((v.z - mu) * inv * wv.z + bv.z),
        f2bf((v.w - mu) * inv * wv.w + bv.w));
}

// -------------------- QKV GEMM: qk[t][2048] + V transposed to vt[B,H,DH,L] ----
__global__ __launch_bounds__(256) void gemm_qkv(
        const unsigned short* __restrict__ A, const unsigned short* __restrict__ B,
        unsigned short* __restrict__ qk, unsigned short* __restrict__ vt) {
    const int K = DD;
    __shared__ unsigned short As[128 * 32];
    __shared__ unsigned short Bs[128 * 32];
    const int tid = threadIdx.x;
    const int w = tid >> 6, lane = tid & 63;
    const int l15 = lane & 15, quad = lane >> 4;
    const int wr = w >> 1, wc = w & 1;
    const int m0 = blockIdx.y << 7, n0 = blockIdx.x << 7;

    const int srow = w * 32 + (lane >> 2);
    const int skel = (lane & 3) << 3;
    const unsigned short* gA = A + (size_t)(m0 + srow) * K + skel;
    const unsigned short* gB = B + (size_t)(n0 + srow) * K + skel;
    unsigned short* lA = &As[w * 1024];
    unsigned short* lB = &Bs[w * 1024];

    f32x4 acc[4][4];
#pragma unroll
    for (int i = 0; i < 4; i++)
#pragma unroll
        for (int j = 0; j < 4; j++) acc[i][j] = (f32x4){0.f, 0.f, 0.f, 0.f};

    for (int k0 = 0; k0 < K; k0 += 32) {
        gload16(gA + k0,                 lA);
        gload16(gA + k0 + (size_t)16*K,  lA + 512);
        gload16(gB + k0,                 lB);
        gload16(gB + k0 + (size_t)16*K,  lB + 512);
        __syncthreads();
        bf16x8 af[4], bg[4];
#pragma unroll
        for (int i = 0; i < 4; i++) {
            af[i] = *(const bf16x8*)&As[(wr*64 + i*16 + l15) * 32 + quad*8];
            bg[i] = *(const bf16x8*)&Bs[(wc*64 + i*16 + l15) * 32 + quad*8];
        }
#pragma unroll
        for (int i = 0; i < 4; i++)
#pragma unroll
            for (int j = 0; j < 4; j++)
                acc[i][j] = mfma16(af[i], bg[j], acc[i][j]);
        __syncthreads();
    }
    if (n0 < D2) {
#pragma unroll
        for (int i = 0; i < 4; i++) {
            const int mrow = m0 + wr*64 + i*16 + quad*4;
#pragma unroll
            for (int j = 0; j < 4; j++) {
                const int ncol = n0 + wc*64 + j*16 + l15;
#pragma unroll
                for (int r = 0; r < 4; r++)
                    qk[(size_t)(mrow + r) * D2 + ncol] = f2bf(acc[i][j][r]);
            }
        }
    } else {
#pragma unroll
        for (int i = 0; i < 4; i++) {
            const int mrow = m0 + wr*64 + i*16 + quad*4;
            const int bb = mrow >> 11, l = mrow & (LL - 1);
#pragma unroll
            for (int j = 0; j < 4; j++) {
                const int nv = n0 + wc*64 + j*16 + l15 - D2;
                const int hh = nv >> 6, dh = nv & 63;
                *(ushort4*)&vt[((size_t)(bb*HH + hh) * DHD + dh) * LL + l] =
                    make_ushort4(f2bf(acc[i][j][0]), f2bf(acc[i][j][1]),
                                 f2bf(acc[i][j][2]), f2bf(acc[i][j][3]));
            }
        }
    }
}

// -------------------- out-proj GEMM, 64x128 tile (2+ blocks/CU) ----------------
__global__ __launch_bounds__(256) void gemm_out(
        const unsigned short* __restrict__ A, const unsigned short* __restrict__ B,
        float* __restrict__ C, int M, int N, int K) {
    __shared__ unsigned short As[64 * 32];
    __shared__ unsigned short Bs[128 * 32];
    const int tid = threadIdx.x;
    const int w = tid >> 6, lane = tid & 63;
    const int l15 = lane & 15, quad = lane >> 4;
    const int wr = w >> 1, wc = w & 1;
    const int m0 = blockIdx.y << 6, n0 = blockIdx.x << 7;
    const int skel = (lane & 3) << 3;
    const unsigned short* gA = A + (size_t)(m0 + w*16 + (lane >> 2)) * K + skel;
    const unsigned short* gB = B + (size_t)(n0 + w*32 + (lane >> 2)) * K + skel;
    unsigned short* lA = &As[w * 512];
    unsigned short* lB = &Bs[w * 1024];
    f32x4 acc[2][4];
#pragma unroll
    for (int i = 0; i < 2; i++)
#pragma unroll
        for (int j = 0; j < 4; j++) acc[i][j] = (f32x4){0.f, 0.f, 0.f, 0.f};
    for (int k0 = 0; k0 < K; k0 += 32) {
        gload16(gA + k0,                 lA);
        gload16(gB + k0,                 lB);
        gload16(gB + k0 + (size_t)16*K,  lB + 512);
        __syncthreads();
        bf16x8 af[2], bg[4];
#pragma unroll
        for (int i = 0; i < 2; i++)
            af[i] = *(const bf16x8*)&As[(wr*32 + i*16 + l15) * 32 + quad*8];
#pragma unroll
        for (int j = 0; j < 4; j++)
            bg[j] = *(const bf16x8*)&Bs[(wc*64 + j*16 + l15) * 32 + quad*8];
#pragma unroll
        for (int i = 0; i < 2; i++)
#pragma unroll
            for (int j = 0; j < 4; j++)
                acc[i][j] = mfma16(af[i], bg[j], acc[i][j]);
        __syncthreads();
    }
#pragma unroll
    for (int i = 0; i < 2; i++) {
        const int mrow = m0 + wr*32 + i*16 + quad*4;
#pragma unroll
        for (int j = 0; j < 4; j++) {
            const int ncol = n0 + wc*64 + j*16 + l15;
#pragma unroll
            for (int r = 0; r < 4; r++)
                C[(size_t)(mrow + r) * N + ncol] = acc[i][j][r];
        }
    }
}

// -------------------- Q/K LayerNorm + NeoX RoPE: qk -> qarr/karr [B,H,L,DH] ----
// Fast transcendentals: freq via exp2, sin/cos via HW v_sin/v_cos (revolutions).
// Q pre-scaled by 0.125*log2(e): attention softmax runs in exp2 domain.
__global__ __launch_bounds__(256) void qk_rope_kernel(
        const unsigned short* __restrict__ qk,
        const float* __restrict__ qw, const float* __restrict__ kw,
        unsigned short* __restrict__ qarr, unsigned short* __restrict__ karr) {
    const int t = blockIdx.x;
    const int l = t & (LL - 1), b = t >> 11;
    const int tid = threadIdx.x;
    const unsigned short* base = qk + (size_t)t * D2;
    const ushort4 qu = *(const ushort4*)(base + tid * 4);
    const ushort4 ku = *(const ushort4*)(base + DD + tid * 4);
    const float q[4] = {bf2f(qu.x), bf2f(qu.y), bf2f(qu.z), bf2f(qu.w)};
    const float k[4] = {bf2f(ku.x), bf2f(ku.y), bf2f(ku.z), bf2f(ku.w)};
    float sq = q[0]+q[1]+q[2]+q[3], ssq = q[0]*q[0]+q[1]*q[1]+q[2]*q[2]+q[3]*q[3];
    float sk = k[0]+k[1]+k[2]+k[3], ssk = k[0]*k[0]+k[1]*k[1]+k[2]*k[2]+k[3]*k[3];
    sq = wred(sq); ssq = wred(ssq); sk = wred(sk); ssk = wred(ssk);
    __shared__ float red[16];
    __shared__ float qs[DD], ks[DD];
    const int wid = tid >> 6;
    if ((tid & 63) == 0) { red[wid] = sq; red[4+wid] = ssq; red[8+wid] = sk; red[12+wid] = ssk; }
    __syncthreads();
    sq = red[0]+red[1]+red[2]+red[3];    ssq = red[4]+red[5]+red[6]+red[7];
    sk = red[8]+red[9]+red[10]+red[11];  ssk = red[12]+red[13]+red[14]+red[15];
    const float muq = sq * (1.f/DD), invq = rsqrtf(ssq*(1.f/DD) - muq*muq + 1e-5f);
    const float muk = sk * (1.f/DD), invk = rsqrtf(ssk*(1.f/DD) - muk*muk + 1e-5f);
    const float4 qwv = ((const float4*)qw)[tid];
    const float4 kwv = ((const float4*)kw)[tid];
    const float qwa[4] = {qwv.x, qwv.y, qwv.z, qwv.w};
    const float kwa[4] = {kwv.x, kwv.y, kwv.z, kwv.w};
    float qn[4], kn[4];
#pragma unroll
    for (int e = 0; e < 4; e++) {
        qn[e] = (q[e] - muq) * invq * qwa[e];
        kn[e] = (k[e] - muk) * invk * kwa[e];
    }
    *(float4*)&qs[tid*4] = make_float4(qn[0], qn[1], qn[2], qn[3]);
    *(float4*)&ks[tid*4] = make_float4(kn[0], kn[1], kn[2], kn[3]);
    __syncthreads();
    const int d = tid * 4, j0 = d & 63;
    const bool first = (j0 < 32);
    const int pt = first ? (tid + 8) : (tid - 8);
    const float4 qp4 = *(const float4*)&qs[pt*4];
    const float4 kp4 = *(const float4*)&ks[pt*4];
    const float qb[4] = {qp4.x, qp4.y, qp4.z, qp4.w};
    const float kb[4] = {kp4.x, kp4.y, kp4.z, kp4.w};
    const float lf = (float)l;
    const float QS = 0.125f * 1.44269504088896340736f;   // 1/sqrt(DH) * log2(e)
    unsigned short oq[4], ok[4];
#pragma unroll
    for (int e = 0; e < 4; e++) {
        const float fi   = (float)((j0 & 31) + e);
        // 10000^(-fi/32)/(2pi) = exp2(-fi*log2(1e4)/32) * (1/2pi)
        const float frev = __builtin_amdgcn_exp2f(fi * -0.41524101186092029f)
                         * 0.15915494309189535f;
        float rev = lf * frev;
        rev -= floorf(rev);
        const float sn = __builtin_amdgcn_sinf(rev);   // sin(2*pi*rev)
        const float c  = __builtin_amdgcn_cosf(rev);   // cos(2*pi*rev)
        float vq, vk;
        if (first) { vq = qn[e]*c - qb[e]*sn; vk = kn[e]*c - kb[e]*sn; }
        else       { vq = qn[e]*c + qb[e]*sn; vk = kn[e]*c + kb[e]*sn; }
        oq[e] = f2bf(vq * QS);
        ok[e] = f2bf(vk);
    }
    const int hh = tid >> 4;
    const int dh = (tid * 4) & 63;
    const size_t ro = ((size_t)(b*HH + hh) * LL + l) * DHD + dh;
    *(ushort4*)(qarr + ro) = make_ushort4(oq[0], oq[1], oq[2], oq[3]);
    *(ushort4*)(karr + ro) = make_ushort4(ok[0], ok[1], ok[2], ok[3]);
}

// -------------------- MFMA flash attention, 128q block, qt=4, in-block split ---
// grid 512 (2 blocks/CU exactly): block = (bh, 128 q-rows) x full kv.
// 4 waves = (wq q-half 64) x (h kv-half 1024). 64-kv tiles, 16 iters.
// All LDS strides 128B + XOR chunk swizzle: beat-conflict-free b128 frags.
// Fixed-shift exp2 softmax; l accumulated in-VALU; in-LDS merge of kv halves;
// coalesced 16B ctx stores.
__global__ __launch_bounds__(256, 2) void attn_kernel(
        const unsigned short* __restrict__ qarr,
        const unsigned short* __restrict__ karr,
        const unsigned short* __restrict__ vt,
        unsigned short* __restrict__ ctxb) {
    const int x = blockIdx.x;
    const int bh = (x & 7) | ((x >> 7) << 3);   // 16 qblks of one head per XCD
    const int qblk = (x >> 3) & 15;
    const int b = bh >> 4, hh = bh & 15;
    const int q0 = qblk << 7;
    const int tid = threadIdx.x, w = tid >> 6, lane = tid & 63;
    const int l15 = lane & 15, quad = lane >> 4;
    const int h  = w & 1;           // kv half
    const int wq = w >> 1;          // q half (64 rows)

    __shared__ union {
        struct {
            unsigned short Ks[2][64 * 64];   // [half][kv 64][dh 64] chunk-xor
            unsigned short Vs[2][64 * 64];   // [half][dh 64][kv 64] chunk-xor
            unsigned short Pw[4][16][72];    // per-wave P relayout (reused per qt)
        } m;                                  // 41984 B
        struct {
            float red[128][68];               // half-1 o dump (fp32)
            float lred[2][128];               // l for both halves
            unsigned short red_bf[128][72];   // final bf16 for coalesced store
        } e;                                  // 54272 B
    } sm;

    const unsigned short* kbase = karr + ((size_t)bh * LL + h * 1024) * DHD;
    const unsigned short* vbase = vt   + (size_t)bh * DHD * LL + h * 1024;

    // Q frags (B-operand): rows q0 + wq*64 + qt*16 + l15
    bf16x8 qf[4][2];
    {
        const unsigned short* qp = qarr + ((size_t)bh*LL + q0 + wq*64 + l15) * DHD + quad*8;
#pragma unroll
        for (int qt = 0; qt < 4; qt++)
#pragma unroll
            for (int c = 0; c < 2; c++)
                qf[qt][c] = *(const bf16x8*)(qp + qt*16*DHD + c*32);
    }

    f32x4 o[4][4];
    float lacc[4] = {0.f, 0.f, 0.f, 0.f};
#pragma unroll
    for (int qt = 0; qt < 4; qt++)
#pragma unroll
        for (int nt = 0; nt < 4; nt++) o[qt][nt] = (f32x4){0.f, 0.f, 0.f, 0.f};

    // staging: wave (wq,h) stages rows [wq*32, +32) of stream h's K and V tiles.
    const int r8 = lane >> 3, c8 = lane & 7;
#define STAGE(KT)                                                                  \
    {                                                                              \
        const int kt_ = (KT);                                                      \
        _Pragma("unroll")                                                          \
        for (int rd = 0; rd < 4; rd++) {                                           \
            const int row = wq*32 + rd*8 + r8;                                     \
            gload16(kbase + (size_t)(kt_*64 + row) * DHD + ((c8 ^ r8) << 3),       \
                    &sm.m.Ks[h][(wq*32 + rd*8) * 64]);                             \
            gload16(vbase + (size_t)row * LL + kt_*64 + ((c8 ^ r8) << 3),          \
                    &sm.m.Vs[h][(wq*32 + rd*8) * 64]);                             \
        }                                                                          \
    }

    STAGE(0);

    for (int kt = 0; kt < 16; kt++) {
        __syncthreads();                    // stage(kt) drained
        bf16x8 kf[4][2], vf[4][2];
#pragma unroll
        for (int t = 0; t < 4; t++)
#pragma unroll
            for (int c = 0; c < 2; c++) {
                const int slot = (quad + c*4) ^ (l15 & 7);
                kf[t][c] = *(const bf16x8*)&sm.m.Ks[h][(t*16 + l15) * 64 + slot*8];
                vf[t][c] = *(const bf16x8*)&sm.m.Vs[h][(t*16 + l15) * 64 + slot*8];
            }
        __syncthreads();                    // reads done; safe to overwrite
        if (kt + 1 < 16) STAGE(kt + 1);

#pragma unroll
        for (int qt = 0; qt < 4; qt++) {
            // S^T = K.Q^T - 64 (fixed softmax shift via C-init)
            f32x4 st[4];
#pragma unroll
            for (int t = 0; t < 4; t++) {
                f32x4 z = (f32x4){-64.f, -64.f, -64.f, -64.f};
                z = mfma16(kf[t][0], qf[qt][0], z);
                z = mfma16(kf[t][1], qf[qt][1], z);
                st[t] = z;
            }
            float ps = 0.f;
#pragma unroll
            for (int t = 0; t < 4; t++) {
                const float p0 = __builtin_amdgcn_exp2f(st[t][0]);
                const float p1 = __builtin_amdgcn_exp2f(st[t][1]);
                const float p2 = __builtin_amdgcn_exp2f(st[t][2]);
                const float p3 = __builtin_amdgcn_exp2f(st[t][3]);
                ps += (p0 + p1) + (p2 + p3);
                uint2 pk;
                pk.x = pack_bf2(p0, p1);
                pk.y = pack_bf2(p2, p3);
                *(uint2*)&sm.m.Pw[w][l15][t*16 + quad*4] = pk;
            }
            lacc[qt] += ps;                 // per-lane partial (quad's kv residues)
            const bf16x8 ap0 = *(const bf16x8*)&sm.m.Pw[w][l15][quad*8];
            const bf16x8 ap1 = *(const bf16x8*)&sm.m.Pw[w][l15][32 + quad*8];
#pragma unroll
            for (int nt = 0; nt < 4; nt++) {
                f32x4 t0 = o[qt][nt];
                t0 = mfma16(ap0, vf[nt][0], t0);
                t0 = mfma16(ap1, vf[nt][1], t0);
                o[qt][nt] = t0;
            }
        }
    }
#undef STAGE

    // cross-quad l reduce: per (qt, l15=q) full row-sum in every lane
    float lq[4];
#pragma unroll
    for (int qt = 0; qt < 4; qt++) {
        float v = lacc[qt];
        v += __shfl_xor(v, 16);
        v += __shfl_xor(v, 32);
        lq[qt] = v;
    }

    // ---- in-block merge of the two kv halves ----
    __syncthreads();                        // main-loop LDS dead
    if (h == 1) {
#pragma unroll
        for (int qt = 0; qt < 4; qt++) {
#pragma unroll
            for (int nt = 0; nt < 4; nt++)
#pragma unroll
                for (int r = 0; r < 4; r++)
                    sm.e.red[wq*64 + qt*16 + quad*4 + r][nt*16 + l15] = o[qt][nt][r];
        }
    }
    if (quad == 0)
#pragma unroll
        for (int qt = 0; qt < 4; qt++)
            sm.e.lred[h][wq*64 + qt*16 + l15] = lq[qt];
    __syncthreads();
    if (h == 0) {
#pragma unroll
        for (int qt = 0; qt < 4; qt++) {
            float inv[4];
#pragma unroll
            for (int r = 0; r < 4; r++) {
                const int tok = wq*64 + qt*16 + quad*4 + r;
                inv[r] = 1.0f / (sm.e.lred[0][tok] + sm.e.lred[1][tok]);
            }
#pragma unroll
            for (int nt = 0; nt < 4; nt++)
#pragma unroll
                for (int r = 0; r < 4; r++) {
                    const int tok = wq*64 + qt*16 + quad*4 + r;
                    const float v = (o[qt][nt][r] + sm.e.red[tok][nt*16 + l15]) * inv[r];
                    sm.e.red_bf[tok][nt*16 + l15] = f2bf(v);
                }
        }
    }
    __syncthreads();
    // coalesced store: 128 tokens x 8 x 16B segments, 4 iters over 256 threads
#pragma unroll
    for (int i = 0; i < 4; i++) {
        const int idx = tid + 256*i;
        const int token = idx >> 3, ch = idx & 7;
        const uint4 vdat = *(const uint4*)&sm.e.red_bf[token][ch*8];
        *(uint4*)&ctxb[(size_t)(b*LL + q0 + token) * DD + hh*DHD + ch*8] = vdat;
    }
}

extern "C" void kernel_launch(void* const* d_in, const int* in_sizes, int n_in,
                              void* d_out, int out_size, void* d_ws, size_t ws_size,
                              hipStream_t stream) {
    const float* x      = (const float*)d_in[0];
    const float* ln_w   = (const float*)d_in[1];
    const float* ln_b   = (const float*)d_in[2];
    const float* w_qkv  = (const float*)d_in[3];
    const float* q_ln_w = (const float*)d_in[4];
    const float* k_ln_w = (const float*)d_in[5];
    const float* w_out  = (const float*)d_in[6];
    float* out = (float*)d_out;

    // workspace map (48 MB), lifetime-aliased:
    //  [0,8M)   h bf16 -> karr [B,H,L,DH] (rope; h dead after gemm_qkv)
    //  [8,24M)  qk bf16 [t][2048] -> ctx bf16 (attn; qk dead after rope)
    //  [24,32M) vt bf16 [B,H,DH,L]
    //  [32,40M) qarr bf16 [B,H,L,DH]
    //  [40,46M) wqb ; [46,48M) wob
    char* ws = (char*)d_ws;
    unsigned short* hb    = (unsigned short*)ws;
    unsigned short* karr  = (unsigned short*)ws;
    unsigned short* qk    = (unsigned short*)(ws + ((size_t)8  << 20));
    unsigned short* ctxb  = (unsigned short*)(ws + ((size_t)8  << 20));
    unsigned short* vtp   = (unsigned short*)(ws + ((size_t)24 << 20));
    unsigned short* qarr  = (unsigned short*)(ws + ((size_t)32 << 20));
    unsigned short* wqb   = (unsigned short*)(ws + ((size_t)40 << 20));
    unsigned short* wob   = (unsigned short*)(ws + ((size_t)46 << 20));

    ln_cvt_kernel<<<NT + 4096, 256, 0, stream>>>(x, ln_w, ln_b, hb,
                                                 w_qkv, wqb, w_out, wob);
    gemm_qkv<<<dim3(D3/128, NT/128), 256, 0, stream>>>(hb, wqb, qk, vtp);
    qk_rope_kernel<<<NT, 256, 0, stream>>>(qk, q_ln_w, k_ln_w, qarr, karr);
    attn_kernel<<<512, 256, 0, stream>>>(qarr, karr, vtp, ctxb);
    gemm_out<<<dim3(DD/128, NT/64), 256, 0, stream>>>(ctxb, wob, out, NT, DD, DD);
}